// Round 6
// baseline (115.138 us; speedup 1.0000x reference)
//
#include <hip/hip_runtime.h>
#include <hip/hip_bf16.h>

// CharLSTM: B=128, TW=256, TC=25, V=128, D=32, H=64 (4H=256), N=32768 seqs.
//
// R6 = R5 (MFMA, hi/lo bf16 split, lane-local gates, pre-scaled EWr) +
// issue-count diet (kernel is issue-bound: VALUBusy 65 + MfmaUtil 27):
//  - rcp merging: c' = (c*di*dg + ng*df) * rcp(di*df*dg)  [3 rcp -> 2 per
//    unit], then PAIRWISE rcp across r for both families: 12 -> 4 rcp per
//    lane-timestep. Pair products bounded ~1e24 << f32 max (4-way is not).
//  - chars staged as BYTE offsets (char*1024); EWr base pre-biased by
//    c16*16 -> prefetch is one v_add per row. ibuf padded -> branchless.
//  - EWr prefetch moved AFTER the MFMA block (hidden under activations,
//    not live across MFMA -> lower peak VGPR).
//  - final h read back from hbuf (hi+lo reconstruction) -> no hfin regs.

#define SEQ_M 16
#define TC_LEN 25
#define H_N 64
#define D_N 32
#define G4_N 256
#define V_N 128

typedef __attribute__((ext_vector_type(8))) short bf16x8;
typedef __attribute__((ext_vector_type(4))) float f32x4;
typedef __attribute__((ext_vector_type(4))) int i32x4;

#define SCALE_SIG (-1.4426950408889634f)   /* -log2(e)  */
#define SCALE_G   ( 2.8853900817779268f)   /* 2*log2(e) */

__device__ __forceinline__ ushort bf16_rne(float x) {
    const uint u = __float_as_uint(x);
    return (ushort)((u + 0x7fffu + ((u >> 16) & 1u)) >> 16);
}
__device__ __forceinline__ float bf16_tof(ushort h) {
    return __uint_as_float(((uint)h) << 16);
}
// swizzled byte offset into a [16][64] bf16 (2 KB) tile
__device__ __forceinline__ int hswz(int row, int kbyte) {
    const int b = row * 128 + kbyte;
    return b ^ ((row & 7) << 4);
}

// ---- prologue: EWr[v][c16][tile] = ((E.W)[v][tile*64+c16] + b) * gate_scale ----
__global__ void ew_precompute(const float* __restrict__ E,
                              const float* __restrict__ W,
                              const float* __restrict__ b,
                              float* __restrict__ EWr) {
    const int v = blockIdx.x;
    const int j = threadIdx.x;           // output col = (j>>6)*64 + (j&63)
    float acc = b[j];
#pragma unroll
    for (int d = 0; d < D_N; ++d)
        acc = fmaf(E[v * D_N + d], W[d * G4_N + j], acc);
    const int tile = j >> 6, c16 = j & 63;
    const float scale = (tile == 2) ? SCALE_G : SCALE_SIG;
    EWr[v * G4_N + c16 * 4 + tile] = acc * scale;
}

__global__ __launch_bounds__(256, 1) void char_lstm_mfma(
    const int* __restrict__ chars,   // [N][25]
    const float* __restrict__ U,     // [64][256]
    const float* __restrict__ EWr,   // [128][64][4] permuted+scaled
    float* __restrict__ out)         // [N][64]
{
    const int j = threadIdx.x;
    const int w = j >> 6;            // wave 0..3
    const int l = j & 63;            // lane
    const int q = l >> 4;            // lane group 0..3
    const int n16 = l & 15;          // 0..15
    const int c16 = w * 16 + n16;    // this thread's unit/col-in-gate
    const int seq0 = blockIdx.x * SEQ_M;

    __shared__ int ibuf[TC_LEN + 1][SEQ_M];          // byte offsets, padded
    __shared__ ushort hbuf[2][2][SEQ_M * H_N];       // [buf][hi/lo], 8 KB

    // stage chars transposed as EWr BYTE offsets (row stride 256*4 = 1024)
    for (int idx = j; idx < TC_LEN * SEQ_M; idx += 256) {
        const int s = idx & 15, tt = idx >> 4;
        ibuf[tt][s] = chars[(seq0 + s) * TC_LEN + tt] << 10;
    }
    if (j < SEQ_M) ibuf[TC_LEN][j] = 0;              // dummy row: branchless
    // zero h buffer 0 (hi+lo planes)
    {
        uint* z = (uint*)&hbuf[0][0][0];
        for (int idx = j; idx < 1024; idx += 256) z[idx] = 0u;
    }

    // ---- preload U fragments (pre-scaled, hi/lo), k-map k = ks*32+8q+e ----
    bf16x8 bh[4][2], bl[4][2];
#pragma unroll
    for (int tile = 0; tile < 4; ++tile) {
        const int colg = tile * 64 + c16;
        const float scale = (tile == 2) ? SCALE_G : SCALE_SIG;
#pragma unroll
        for (int ks = 0; ks < 2; ++ks) {
#pragma unroll
            for (int e = 0; e < 8; ++e) {
                const int k = ks * 32 + 8 * q + e;
                const float uv = U[k * G4_N + colg] * scale;
                const ushort hi = bf16_rne(uv);
                bh[tile][ks][e] = (short)hi;
                bl[tile][ks][e] = (short)bf16_rne(uv - bf16_tof(hi));
            }
        }
    }

    __syncthreads();

    // hoisted LDS offsets + pre-biased EWr byte base
    const int offA0 = hswz(n16, 16 * q);
    const int offA1 = hswz(n16, 64 + 16 * q);
    int offW[4];
#pragma unroll
    for (int r = 0; r < 4; ++r) offW[r] = hswz(4 * q + r, c16 * 2);
    const char* ewb = (const char*)EWr + c16 * 16;

    // ---- EWr rows for t=0 ----
    f32x4 ewv[4];
    {
        const i32x4 cv = *(const i32x4*)&ibuf[0][4 * q];
#pragma unroll
        for (int r = 0; r < 4; ++r)
            ewv[r] = *(const f32x4*)(ewb + cv[r]);
    }

    float c[4] = {0.0f, 0.0f, 0.0f, 0.0f};
    int cur = 0;

    for (int t = 0; t < TC_LEN; ++t) {
        // acc init: acc[tile][r] = ewv[r][tile]  (scaled z from x-proj)
        f32x4 acc[4];
#pragma unroll
        for (int tile = 0; tile < 4; ++tile) {
            acc[tile][0] = ewv[0][tile];
            acc[tile][1] = ewv[1][tile];
            acc[tile][2] = ewv[2][tile];
            acc[tile][3] = ewv[3][tile];
        }

        // A fragments (hi/lo planes of h)
        const char* hb_hi = (const char*)&hbuf[cur][0][0];
        const char* hb_lo = (const char*)&hbuf[cur][1][0];
        const bf16x8 ah0 = *(const bf16x8*)(hb_hi + offA0);
        const bf16x8 ah1 = *(const bf16x8*)(hb_hi + offA1);
        const bf16x8 al0 = *(const bf16x8*)(hb_lo + offA0);
        const bf16x8 al1 = *(const bf16x8*)(hb_lo + offA1);

        // z += h.U : 3-term hi/lo split, 24 MFMA
#pragma unroll
        for (int tile = 0; tile < 4; ++tile) {
            acc[tile] = __builtin_amdgcn_mfma_f32_16x16x32_bf16(ah0, bh[tile][0], acc[tile], 0, 0, 0);
            acc[tile] = __builtin_amdgcn_mfma_f32_16x16x32_bf16(ah0, bl[tile][0], acc[tile], 0, 0, 0);
            acc[tile] = __builtin_amdgcn_mfma_f32_16x16x32_bf16(al0, bh[tile][0], acc[tile], 0, 0, 0);
            acc[tile] = __builtin_amdgcn_mfma_f32_16x16x32_bf16(ah1, bh[tile][1], acc[tile], 0, 0, 0);
            acc[tile] = __builtin_amdgcn_mfma_f32_16x16x32_bf16(ah1, bl[tile][1], acc[tile], 0, 0, 0);
            acc[tile] = __builtin_amdgcn_mfma_f32_16x16x32_bf16(al1, bh[tile][1], acc[tile], 0, 0, 0);
        }

        // prefetch next timestep's EW rows (dummy row t=25 -> branchless;
        // consumed next iteration, hidden under the activation section)
        {
            const i32x4 cv = *(const i32x4*)&ibuf[t + 1][4 * q];
#pragma unroll
            for (int r = 0; r < 4; ++r)
                ewv[r] = *(const f32x4*)(ewb + cv[r]);
        }

        // ---- activations; acc pre-scaled -> exp2 directly ----
        // family 1: c' = (c*di*dg + ng*df) * rcp(di*df*dg), rcp paired over r
        float m1[4], Pf[4], num[4], e2g_[4];
#pragma unroll
        for (int r = 0; r < 4; ++r) {
            const float A  = __builtin_amdgcn_exp2f(acc[0][r]);   // e^-zi
            const float B  = __builtin_amdgcn_exp2f(acc[1][r]);   // e^-zf
            const float C  = __builtin_amdgcn_exp2f(acc[2][r]);   // e^2zg
            e2g_[r] = C;
            const float di = 1.0f + A;
            const float df = 1.0f + B;
            const float dg = 1.0f + C;
            m1[r]  = di * dg;
            Pf[r]  = m1[r] * df;
            num[r] = fmaf(c[r], m1[r], (C - 1.0f) * df);
        }
        {
            const float Q01 = __builtin_amdgcn_rcpf(Pf[0] * Pf[1]);
            const float Q23 = __builtin_amdgcn_rcpf(Pf[2] * Pf[3]);
            c[0] = num[0] * (Q01 * Pf[1]);
            c[1] = num[1] * (Q01 * Pf[0]);
            c[2] = num[2] * (Q23 * Pf[3]);
            c[3] = num[3] * (Q23 * Pf[2]);
        }
        // family 2: h = nh * rcp(do_*dh), rcp paired over r
        float nh[4], Ph[4];
#pragma unroll
        for (int r = 0; r < 4; ++r) {
            const float D   = __builtin_amdgcn_exp2f(acc[3][r]);  // e^-zo
            const float E   = __builtin_amdgcn_exp2f(c[r] * SCALE_G);
            nh[r] = E - 1.0f;
            Ph[r] = (1.0f + D) * (E + 1.0f);
        }
        char* hn_hi = (char*)&hbuf[cur ^ 1][0][0];
        char* hn_lo = (char*)&hbuf[cur ^ 1][1][0];
        {
            const float Q01 = __builtin_amdgcn_rcpf(Ph[0] * Ph[1]);
            const float Q23 = __builtin_amdgcn_rcpf(Ph[2] * Ph[3]);
            const float h0 = nh[0] * (Q01 * Ph[1]);
            const float h1 = nh[1] * (Q01 * Ph[0]);
            const float h2 = nh[2] * (Q23 * Ph[3]);
            const float h3 = nh[3] * (Q23 * Ph[2]);
            const float hh[4] = {h0, h1, h2, h3};
#pragma unroll
            for (int r = 0; r < 4; ++r) {
                // truncation hi/lo split (err ~2^-17)
                const uint hu = __float_as_uint(hh[r]);
                const float hi_f = __uint_as_float(hu & 0xffff0000u);
                const float lo_f = hh[r] - hi_f;
                *(ushort*)(hn_hi + offW[r]) = (ushort)(hu >> 16);
                *(ushort*)(hn_lo + offW[r]) = (ushort)(__float_as_uint(lo_f) >> 16);
            }
        }
        __syncthreads();
        cur ^= 1;
    }

    // ---- write h_last: reconstruct from hbuf hi+lo (err ~2^-17) ----
    const char* hf_hi = (const char*)&hbuf[cur][0][0];
    const char* hf_lo = (const char*)&hbuf[cur][1][0];
#pragma unroll
    for (int r = 0; r < 4; ++r) {
        const ushort hi = *(const ushort*)(hf_hi + offW[r]);
        const ushort lo = *(const ushort*)(hf_lo + offW[r]);
        out[(seq0 + 4 * q + r) * H_N + c16] = bf16_tof(hi) + bf16_tof(lo);
    }
}

extern "C" void kernel_launch(void* const* d_in, const int* in_sizes, int n_in,
                              void* d_out, int out_size, void* d_ws, size_t ws_size,
                              hipStream_t stream) {
    const int*   chars = (const int*)d_in[0];
    const float* E     = (const float*)d_in[1];
    const float* W     = (const float*)d_in[2];
    const float* U     = (const float*)d_in[3];
    const float* b     = (const float*)d_in[4];
    float* out = (float*)d_out;
    float* EWr = (float*)d_ws;                      // 131072 B

    const int N = in_sizes[0] / TC_LEN;             // 32768
    const int blocks = N / SEQ_M;                   // 2048

    ew_precompute<<<V_N, G4_N, 0, stream>>>(E, W, b, EWr);
    char_lstm_mfma<<<blocks, 256, 0, stream>>>(chars, U, EWr, out);
}